// Round 20
// baseline (84.386 us; speedup 1.0000x reference)
//
#include <hip/hip_runtime.h>
#include <hip/hip_bf16.h>

// MechanicsPINN: residual = EI*biharm(f) + GC*lap(f) + KC*f - P,
// f = MLP(x) 2->256->512->1024->65536, B=64, grid 256x256. All inputs fp32.
// Round 20: gemm at the untried lattice cell (1KB segments, 16 waves/CU):
// ONE 1024-thread block per CU (grid 256), 256-col x 32-k W tile (each k-row
// = 1KB contiguous HBM), double-buffered global_load_lds, R12/R17 counted
// vmcnt schedule. Per thread per step: 2x16B W + 1x4B A -> uniform vmcnt(3).
// Epilogue reuses the 64KB Wt as full 64x256 C buffer -> 1KB store segments.
// MLP (layer12 scalar, layer3 single-wave MFMA) + stencil = R19 exact.

#define BATCH 64
#define NPIX 65536

typedef __attribute__((ext_vector_type(8))) short short8_t;  // bf16 x8 (4 VGPR)
typedef __attribute__((ext_vector_type(4))) float f32x4;

__device__ __forceinline__ short f2bf(float x) {  // fp32 -> bf16 RNE (native)
    __hip_bfloat16 h = __float2bfloat16(x);
    short s;
    __builtin_memcpy(&s, &h, 2);
    return s;
}

// -------- Fused layers 1+2: h2b = bf16(relu(relu(x@W1+b1) @ W2 + b2)) --------
__global__ void k_layer12(const float* __restrict__ x, const float* __restrict__ W1,
                          const float* __restrict__ b1, const float* __restrict__ W2,
                          const float* __restrict__ b2, short* __restrict__ h2b) {
    __shared__ float As[16][64];
    __shared__ float Ws[64][16];
    int tid = threadIdx.x;
    int tn = tid & 15, tm = tid >> 4;
    int n0 = blockIdx.x * 16, m0 = blockIdx.y * 16;
    float acc = 0.f;
    for (int k0 = 0; k0 < 256; k0 += 64) {
#pragma unroll
        for (int j = 0; j < 4; ++j) {          // build h1 16x64 tile on the fly
            int e = j * 256 + tid;
            int m = m0 + (e >> 6), kk = k0 + (e & 63);
            float v = x[m * 2 + 0] * W1[kk] + x[m * 2 + 1] * W1[256 + kk] + b1[kk];
            As[e >> 6][e & 63] = v > 0.f ? v : 0.f;
        }
#pragma unroll
        for (int j = 0; j < 4; ++j) {          // stage W2 64x16
            int e = j * 256 + tid;
            Ws[e >> 4][e & 15] = W2[(k0 + (e >> 4)) * 512 + n0 + (e & 15)];
        }
        __syncthreads();
#pragma unroll
        for (int k = 0; k < 64; ++k)
            acc += As[tm][k] * Ws[k][tn];
        __syncthreads();
    }
    acc += b2[n0 + tn];
    acc = acc > 0.f ? acc : 0.f;
    h2b[(m0 + tm) * 512 + n0 + tn] = f2bf(acc);
}

// -------- Layer 3 (MFMA): h3b = bf16(relu(h2b @ W3 + b3)) — R19 exact --------
__global__ __launch_bounds__(64) void k_layer3(
        const short* __restrict__ A,     // h2b bf16 [64][512]
        const float* __restrict__ W3,    // [512][1024]
        const float* __restrict__ b3,    // [1024]
        short* __restrict__ h3b) {       // [64][1024] bf16
    __shared__ float Wt[2][32 * 16];     // 2KB per buffer, [k][col]
    const int lane = threadIdx.x;
    const int lr = lane & 15;
    const int g = lane >> 4;             // k-group 0..3
    const int n0 = blockIdx.x * 16;

    f32x4 acc[4];
#pragma unroll
    for (int a = 0; a < 4; ++a) acc[a] = {0.f, 0.f, 0.f, 0.f};

    const short* ap = A + lr * 512 + g * 8;

    auto stage = [&](int b, int s) {
#pragma unroll
        for (int i = 0; i < 2; ++i) {
            int c = i * 64 + lane;
            int k = c >> 2, q = c & 3;
            const float* src = W3 + (size_t)(s * 32 + k) * 1024 + n0 + q * 4;
            __builtin_amdgcn_global_load_lds(
                (const __attribute__((address_space(1))) void*)src,
                (__attribute__((address_space(3))) void*)((char*)&Wt[b][0] + c * 16),
                16, 0, 0);
        }
    };

    short8_t aC[4], aN[4];
    stage(0, 0);
#pragma unroll
    for (int mt = 0; mt < 4; ++mt)
        aC[mt] = *(const short8_t*)(ap + mt * 8192);

    for (int s = 0; s < 16; ++s) {
        const int cur = s & 1;
        if (s < 15) {
            stage(cur ^ 1, s + 1);
#pragma unroll
            for (int mt = 0; mt < 4; ++mt)
                aN[mt] = *(const short8_t*)(ap + mt * 8192 + (s + 1) * 32);
            asm volatile("s_waitcnt vmcnt(6)" ::: "memory");
        } else {
            asm volatile("s_waitcnt vmcnt(0)" ::: "memory");
        }
        __builtin_amdgcn_sched_barrier(0);

        short8_t bfr;
#pragma unroll
        for (int j = 0; j < 8; ++j)
            bfr[j] = f2bf(Wt[cur][(g * 8 + j) * 16 + lr]);
#pragma unroll
        for (int mt = 0; mt < 4; ++mt)
            acc[mt] = __builtin_amdgcn_mfma_f32_16x16x32_bf16(aC[mt], bfr, acc[mt], 0, 0, 0);

        if (s < 15) {
#pragma unroll
            for (int mt = 0; mt < 4; ++mt) aC[mt] = aN[mt];
        }
    }

    float bb = b3[n0 + lr];
#pragma unroll
    for (int mt = 0; mt < 4; ++mt) {
        int rowb = mt * 16 + g * 4;
#pragma unroll
        for (int r = 0; r < 4; ++r) {
            float v = acc[mt][r] + bb;
            v = v > 0.f ? v : 0.f;
            h3b[(rowb + r) * 1024 + n0 + lr] = f2bf(v);
        }
    }
}

// ---------- Main GEMM: f = h3b @ W4 + b4 (bf16 MFMA, M=64,N=65536,K=1024) ----
// 1024 thr / 16 waves, grid 256 (1 block/CU). Block tile = 256 cols x 64 m.
// Wave w owns cols w*16..+15 (1 col-tile x 4 m-tiles = 4 MFMA per 32-k step).
__global__ __launch_bounds__(1024) void k_gemm_mfma(
        const short* __restrict__ A,     // h3 bf16 [64][1024]
        const float* __restrict__ W,     // W4 fp32 [1024][65536]
        const float* __restrict__ bias,  // [65536]
        float* __restrict__ f) {         // [64][65536]
    __shared__ float Wt[2][32 * 256];    // 32 KB per buffer, [k][col^swz]
    __shared__ short At[2][4 * 64 * 8];  // 4 KB per buffer, [kq][m^swz][8]
    const int tid = threadIdx.x;
    const int w = tid >> 6;              // 0..15
    const int lane = tid & 63;
    const int lr = lane & 15;
    const int g = lane >> 4;             // k-group 0..3
    const int n0 = blockIdx.x * 256;

    f32x4 acc[4];                        // [m-tile]
#pragma unroll
    for (int a = 0; a < 4; ++a)
        acc[a] = {0.f, 0.f, 0.f, 0.f};

    // stage step s into buffer b: 2 W-chunks (16B) + 1 A-chunk (4B) per thread
    auto stage = [&](int b, int s) {
#pragma unroll
        for (int i = 0; i < 2; ++i) {
            int c = i * 1024 + tid;                // 0..2047
            int k = c >> 6;                        // 0..31 (64 chunks per k-row)
            int q4 = (c & 63) * 4;                 // float col offset
            int csw = q4 ^ (((k >> 3) & 1) << 4);  // source pre-swizzle (bit4)
            const float* src = W + (size_t)(s * 32 + k) * NPIX + n0 + csw;
            __builtin_amdgcn_global_load_lds(
                (const __attribute__((address_space(1))) void*)src,
                (__attribute__((address_space(3))) void*)((char*)&Wt[b][0] + c * 16),
                16, 0, 0);
        }
        {
            int c = tid >> 2, q = tid & 3;         // chunk 0..255, 4B quarter
            int kq = c >> 6;                       // 0..3
            int md = (c & 63) ^ (kq << 2);         // source m pre-swizzle
            const short* asrc = A + md * 1024 + s * 32 + kq * 8 + q * 2;
            __builtin_amdgcn_global_load_lds(
                (const __attribute__((address_space(1))) void*)asrc,
                (__attribute__((address_space(3))) void*)((char*)&At[b][0] + tid * 4),
                4, 0, 0);
        }
    };

    stage(0, 0);

    for (int s = 0; s < 32; ++s) {
        const int cur = s & 1;
        if (s < 31) {
            stage(cur ^ 1, s + 1);                 // issue next step's loads
            asm volatile("s_waitcnt vmcnt(3)" ::: "memory");  // stage(s) landed
        } else {
            asm volatile("s_waitcnt vmcnt(0)" ::: "memory");
        }
        __builtin_amdgcn_sched_barrier(0);
        __builtin_amdgcn_s_barrier();    // everyone's stage(s) landed
        __builtin_amdgcn_sched_barrier(0);

        // A-frags: [kq=g][(mrow^(g<<2))]
        short8_t afr[4];
#pragma unroll
        for (int mt = 0; mt < 4; ++mt) {
            int mrow = mt * 16 + lr;
            afr[mt] = *(const short8_t*)((const short*)&At[cur][0] +
                                         g * 512 + (mrow ^ (g << 2)) * 8);
        }
        {
            const int col = w * 16 + lr;
            const int csw = col ^ ((g & 1) << 4);  // undo bit-4 swizzle
            short8_t bfr;
#pragma unroll
            for (int j = 0; j < 8; ++j)
                bfr[j] = f2bf(Wt[cur][(g * 8 + j) * 256 + csw]);
#pragma unroll
            for (int mt = 0; mt < 4; ++mt)
                acc[mt] = __builtin_amdgcn_mfma_f32_16x16x32_bf16(afr[mt], bfr, acc[mt], 0, 0, 0);
        }
        __builtin_amdgcn_s_barrier();    // reads of cur done before overwrite
    }

    // ---- coalesced epilogue: dump C (+bias) to 64KB LDS, 1KB store rows ----
    __syncthreads();
    float* Cl = (float*)&Wt[0][0];       // 64 rows x 256 cols = 64 KB
    {
        const int colb = w * 16 + lr;
        float bb = bias[n0 + colb];
#pragma unroll
        for (int mt = 0; mt < 4; ++mt)
#pragma unroll
            for (int r = 0; r < 4; ++r)
                Cl[(mt * 16 + g * 4 + r) * 256 + colb] = acc[mt][r] + bb;
    }
    __syncthreads();
#pragma unroll
    for (int it = 0; it < 4; ++it) {     // 1024 thr: 64-lane group per row
        int row = (tid >> 6) + it * 16;  // 0..63
        int cc = (tid & 63) * 4;         // float offset 0..252
        f32x4 v = *(const f32x4*)&Cl[row * 256 + cc];
        *(f32x4*)(f + (size_t)row * NPIX + n0 + cc) = v;
    }
}

// --------------------------- Stencil (two-phase, R17/R19 exact) --------------
#define ROWS 16
__device__ __forceinline__ int rfl(int i) {
    return i < 0 ? -i : (i > 255 ? 510 - i : i);
}
__global__ void k_stencil(const float* __restrict__ f, const float* __restrict__ P,
                          float* __restrict__ out) {
    __shared__ float fs[ROWS + 4][256];
    __shared__ float ls[ROWS + 2][256];
    int x = threadIdx.x;
    int y0 = blockIdx.x * ROWS;
    int b = blockIdx.y;
    const float* fb = f + (size_t)b * NPIX;
#pragma unroll
    for (int t = 0; t < ROWS + 4; ++t) {
        int gy = rfl(y0 - 2 + t);
        fs[t][x] = fb[gy * 256 + x];
    }
    __syncthreads();

    int xm = x == 0 ? 1 : x - 1;
    int xp = x == 255 ? 254 : x + 1;

#pragma unroll
    for (int t = 0; t < ROWS + 2; ++t) {
        int jj = rfl(y0 - 1 + t);
        int s  = jj - y0 + 2;
        int sm = rfl(jj - 1) - y0 + 2;
        int sp = rfl(jj + 1) - y0 + 2;
        float c = fs[s][x];
        ls[t][x] = (fs[sm][x] - 2.f * c + fs[sp][x]) +
                   (fs[s][xm] - 2.f * c + fs[s][xp]);
    }
    __syncthreads();

#pragma unroll
    for (int r = 0; r < ROWS; ++r) {
        int y = y0 + r;
        float lc = ls[r + 1][x];
        float bih = (ls[r][x] - 2.f * lc + ls[r + 2][x]) +
                    (ls[r + 1][xm] - 2.f * lc + ls[r + 1][xp]);
        float fc = fs[r + 2][x];
        size_t idx = (size_t)b * NPIX + y * 256 + x;
        out[idx] = bih + lc + fc - P[idx];
    }
}

extern "C" void kernel_launch(void* const* d_in, const int* in_sizes, int n_in,
                              void* d_out, int out_size, void* d_ws, size_t ws_size,
                              hipStream_t stream) {
    const float* x  = (const float*)d_in[0];
    const float* P  = (const float*)d_in[1];
    const float* W1 = (const float*)d_in[2];
    const float* b1 = (const float*)d_in[3];
    const float* W2 = (const float*)d_in[4];
    const float* b2 = (const float*)d_in[5];
    const float* W3 = (const float*)d_in[6];
    const float* b3 = (const float*)d_in[7];
    const float* W4 = (const float*)d_in[8];
    const float* b4 = (const float*)d_in[9];
    float* out = (float*)d_out;

    char* ws = (char*)d_ws;
    short* h2b = (short*)(ws);                      // 64*512*2  = 64 KB
    short* h3b = (short*)(ws + (128 << 10));        // 64*1024*2 = 128 KB (bf16)
    float* f   = (float*)(ws + (256 << 10));        // 64*65536*4 = 16 MB

    k_layer12<<<dim3(512 / 16, 4), 256, 0, stream>>>(x, W1, b1, W2, b2, h2b);
    k_layer3<<<64, 64, 0, stream>>>(h2b, W3, b3, h3b);
    k_gemm_mfma<<<NPIX / 256, 1024, 0, stream>>>(h3b, W4, b4, f);
    k_stencil<<<dim3(256 / ROWS, BATCH), 256, 0, stream>>>(f, P, out);
}

// Round 21
// 76.974 us; speedup vs baseline: 1.0963x; 1.0963x over previous
//
#include <hip/hip_runtime.h>
#include <hip/hip_bf16.h>

// MechanicsPINN: residual = EI*biharm(f) + GC*lap(f) + KC*f - P,
// f = MLP(x) 2->256->512->1024->65536, B=64, grid 256x256. All inputs fp32.
// Round 21: gemm + layer3 + stencil = R19 EXACT (77.9 us best).
// New: k_layer12 as single-wave MFMA (grid 32 x 64thr, zero barriers,
// counted vmcnt(2) W2 double-buffer; h1 = relu(x@W1+b1) computed in-register
// from hoisted W1/b1 slices -- K=2, so 2 FMA per element).

#define BATCH 64
#define NPIX 65536

typedef __attribute__((ext_vector_type(8))) short short8_t;  // bf16 x8 (4 VGPR)
typedef __attribute__((ext_vector_type(4))) float f32x4;

__device__ __forceinline__ short f2bf(float x) {  // fp32 -> bf16 RNE (native)
    __hip_bfloat16 h = __float2bfloat16(x);
    short s;
    __builtin_memcpy(&s, &h, 2);
    return s;
}

// -------- Layers 1+2 (MFMA): h2b = bf16(relu(relu(x@W1+b1) @ W2 + b2)) ------
// Grid 32 x 64 thr (1 wave). Wave owns 16 cols x all 64 m, K=256 -> 8 steps.
// W2 staged 32x16 fp32 (2KB) double-buffered via global_load_lds; zero
// barriers (single wave; vmcnt is the sync). A-frags (h1) computed in-reg:
// W1 rows + b1 hoisted to VGPRs in the prologue (static unroll indexing).
__global__ __launch_bounds__(64) void k_layer12(
        const float* __restrict__ x,     // [64][2]
        const float* __restrict__ W1,    // [2][256]
        const float* __restrict__ b1,    // [256]
        const float* __restrict__ W2,    // [256][512]
        const float* __restrict__ b2,    // [512]
        short* __restrict__ h2b) {       // [64][512] bf16
    __shared__ float Wt[2][32 * 16];     // 2KB per buffer, [k][col]
    const int lane = threadIdx.x;
    const int lr = lane & 15;
    const int g = lane >> 4;             // k-group 0..3
    const int n0 = blockIdx.x * 16;

    f32x4 acc[4];
#pragma unroll
    for (int a = 0; a < 4; ++a) acc[a] = {0.f, 0.f, 0.f, 0.f};

    // hoist x rows (this lane's 4 m-rows) and W1/b1 slices (all 8 steps)
    float x0[4], x1[4];
#pragma unroll
    for (int mt = 0; mt < 4; ++mt) {
        x0[mt] = x[(mt * 16 + lr) * 2 + 0];
        x1[mt] = x[(mt * 16 + lr) * 2 + 1];
    }
    f32x4 w0v[16], w1v[16], bv[16];      // [s*2+h]: k = s*32 + g*8 + h*4
#pragma unroll
    for (int i = 0; i < 16; ++i) {
        int kb = (i >> 1) * 32 + g * 8 + (i & 1) * 4;
        w0v[i] = *(const f32x4*)(W1 + kb);
        w1v[i] = *(const f32x4*)(W1 + 256 + kb);
        bv[i]  = *(const f32x4*)(b1 + kb);
    }

    auto stage = [&](int b, int s) {
#pragma unroll
        for (int i = 0; i < 2; ++i) {
            int c = i * 64 + lane;             // 0..127
            int k = c >> 2, q = c & 3;         // 4 chunks (64B) per k-row
            const float* src = W2 + (size_t)(s * 32 + k) * 512 + n0 + q * 4;
            __builtin_amdgcn_global_load_lds(
                (const __attribute__((address_space(1))) void*)src,
                (__attribute__((address_space(3))) void*)((char*)&Wt[b][0] + c * 16),
                16, 0, 0);
        }
    };

    stage(0, 0);

#pragma unroll
    for (int s = 0; s < 8; ++s) {
        const int cur = s & 1;
        if (s < 7) {
            stage(cur ^ 1, s + 1);             // 2 DMA in flight
            asm volatile("s_waitcnt vmcnt(2)" ::: "memory");  // stage(s) landed
        } else {
            asm volatile("s_waitcnt vmcnt(0)" ::: "memory");
        }
        __builtin_amdgcn_sched_barrier(0);

        // A-frags: h1[mt*16+lr][s*32+g*8+j] = relu(x0*W1r0 + x1*W1r1 + b1)
        short8_t afr[4];
#pragma unroll
        for (int mt = 0; mt < 4; ++mt)
#pragma unroll
            for (int j = 0; j < 8; ++j) {
                float v = x0[mt] * w0v[s * 2 + (j >> 2)][j & 3]
                        + x1[mt] * w1v[s * 2 + (j >> 2)][j & 3]
                        + bv[s * 2 + (j >> 2)][j & 3];
                afr[mt][j] = f2bf(v > 0.f ? v : 0.f);
            }

        short8_t bfr;
#pragma unroll
        for (int j = 0; j < 8; ++j)            // col=lr, k=g*8+j
            bfr[j] = f2bf(Wt[cur][(g * 8 + j) * 16 + lr]);
#pragma unroll
        for (int mt = 0; mt < 4; ++mt)
            acc[mt] = __builtin_amdgcn_mfma_f32_16x16x32_bf16(afr[mt], bfr, acc[mt], 0, 0, 0);
    }

    // C/D: col = lane&15, row = mt*16 + g*4 + r
    float bb = b2[n0 + lr];
#pragma unroll
    for (int mt = 0; mt < 4; ++mt) {
        int rowb = mt * 16 + g * 4;
#pragma unroll
        for (int r = 0; r < 4; ++r) {
            float v = acc[mt][r] + bb;
            v = v > 0.f ? v : 0.f;             // relu
            h2b[(rowb + r) * 512 + n0 + lr] = f2bf(v);
        }
    }
}

// -------- Layer 3 (MFMA): h3b = bf16(relu(h2b @ W3 + b3)) — R19 exact --------
__global__ __launch_bounds__(64) void k_layer3(
        const short* __restrict__ A,     // h2b bf16 [64][512]
        const float* __restrict__ W3,    // [512][1024]
        const float* __restrict__ b3,    // [1024]
        short* __restrict__ h3b) {       // [64][1024] bf16
    __shared__ float Wt[2][32 * 16];     // 2KB per buffer, [k][col]
    const int lane = threadIdx.x;
    const int lr = lane & 15;
    const int g = lane >> 4;             // k-group 0..3
    const int n0 = blockIdx.x * 16;

    f32x4 acc[4];
#pragma unroll
    for (int a = 0; a < 4; ++a) acc[a] = {0.f, 0.f, 0.f, 0.f};

    const short* ap = A + lr * 512 + g * 8;

    auto stage = [&](int b, int s) {
#pragma unroll
        for (int i = 0; i < 2; ++i) {
            int c = i * 64 + lane;
            int k = c >> 2, q = c & 3;
            const float* src = W3 + (size_t)(s * 32 + k) * 1024 + n0 + q * 4;
            __builtin_amdgcn_global_load_lds(
                (const __attribute__((address_space(1))) void*)src,
                (__attribute__((address_space(3))) void*)((char*)&Wt[b][0] + c * 16),
                16, 0, 0);
        }
    };

    short8_t aC[4], aN[4];
    stage(0, 0);
#pragma unroll
    for (int mt = 0; mt < 4; ++mt)
        aC[mt] = *(const short8_t*)(ap + mt * 8192);

    for (int s = 0; s < 16; ++s) {
        const int cur = s & 1;
        if (s < 15) {
            stage(cur ^ 1, s + 1);
#pragma unroll
            for (int mt = 0; mt < 4; ++mt)
                aN[mt] = *(const short8_t*)(ap + mt * 8192 + (s + 1) * 32);
            asm volatile("s_waitcnt vmcnt(6)" ::: "memory");
        } else {
            asm volatile("s_waitcnt vmcnt(0)" ::: "memory");
        }
        __builtin_amdgcn_sched_barrier(0);

        short8_t bfr;
#pragma unroll
        for (int j = 0; j < 8; ++j)
            bfr[j] = f2bf(Wt[cur][(g * 8 + j) * 16 + lr]);
#pragma unroll
        for (int mt = 0; mt < 4; ++mt)
            acc[mt] = __builtin_amdgcn_mfma_f32_16x16x32_bf16(aC[mt], bfr, acc[mt], 0, 0, 0);

        if (s < 15) {
#pragma unroll
            for (int mt = 0; mt < 4; ++mt) aC[mt] = aN[mt];
        }
    }

    float bb = b3[n0 + lr];
#pragma unroll
    for (int mt = 0; mt < 4; ++mt) {
        int rowb = mt * 16 + g * 4;
#pragma unroll
        for (int r = 0; r < 4; ++r) {
            float v = acc[mt][r] + bb;
            v = v > 0.f ? v : 0.f;
            h3b[(rowb + r) * 1024 + n0 + lr] = f2bf(v);
        }
    }
}

// ---------- Main GEMM: f = h3b @ W4 + b4 (bf16 MFMA) — R17/R19 exact ---------
__global__ __launch_bounds__(256) void k_gemm_mfma(
        const short* __restrict__ A,     // h3 bf16 [64][1024]
        const float* __restrict__ W,     // W4 fp32 [1024][65536]
        const float* __restrict__ bias,  // [65536]
        float* __restrict__ f) {         // [64][65536]
    __shared__ float Wt[2][32 * 128];    // 16 KB per buffer, [k][col^swz]
    __shared__ short At[2][4 * 64 * 8];  // 4 KB per buffer, [kq][m^swz][8]
    const int tid = threadIdx.x;
    const int w = tid >> 6;
    const int lane = tid & 63;
    const int lr = lane & 15;
    const int g = lane >> 4;             // k-group 0..3
    const int n0 = blockIdx.x * 128;

    f32x4 acc[4][2];                     // [m-tile][col-tile]
#pragma unroll
    for (int a = 0; a < 4; ++a)
#pragma unroll
        for (int b = 0; b < 2; ++b)
            acc[a][b] = {0.f, 0.f, 0.f, 0.f};

    // stage step s into buffer b: 4 W-chunks + 1 A-chunk per thread (16B each)
    auto stage = [&](int b, int s) {
#pragma unroll
        for (int i = 0; i < 4; ++i) {
            int c = i * 256 + tid;                 // 0..1023
            int k = c >> 5;                        // 0..31
            int q4 = (c & 31) * 4;                 // float col-group
            int csw = q4 ^ (((k >> 3) & 1) << 4);  // source pre-swizzle (bit4)
            const float* src = W + (size_t)(s * 32 + k) * NPIX + n0 + csw;
            __builtin_amdgcn_global_load_lds(
                (const __attribute__((address_space(1))) void*)src,
                (__attribute__((address_space(3))) void*)((char*)&Wt[b][0] + c * 16),
                16, 0, 0);
        }
        {
            int kq = tid >> 6;                     // 0..3
            int ms = tid & 63;
            int md = ms ^ (kq << 2);               // source m pre-swizzle
            const short* asrc = A + md * 1024 + s * 32 + kq * 8;
            __builtin_amdgcn_global_load_lds(
                (const __attribute__((address_space(1))) void*)asrc,
                (__attribute__((address_space(3))) void*)((char*)&At[b][0] + tid * 16),
                16, 0, 0);
        }
    };

    stage(0, 0);

    for (int s = 0; s < 32; ++s) {
        const int cur = s & 1;
        if (s < 31) {
            stage(cur ^ 1, s + 1);
            asm volatile("s_waitcnt vmcnt(5)" ::: "memory");  // stage(s) landed
        } else {
            asm volatile("s_waitcnt vmcnt(0)" ::: "memory");
        }
        __builtin_amdgcn_sched_barrier(0);
        __builtin_amdgcn_s_barrier();    // everyone's stage(s) landed
        __builtin_amdgcn_sched_barrier(0);

        // A-frags: [kq=g][(mrow^(g<<2))]
        short8_t afr[4];
#pragma unroll
        for (int mt = 0; mt < 4; ++mt) {
            int mrow = mt * 16 + lr;
            afr[mt] = *(const short8_t*)((const short*)&At[cur][0] +
                                         g * 512 + (mrow ^ (g << 2)) * 8);
        }
#pragma unroll
        for (int t = 0; t < 2; ++t) {
            const int col = w * 32 + t * 16 + lr;
            const int csw = col ^ ((g & 1) << 4);  // undo bit-4 swizzle
            short8_t bfr;
#pragma unroll
            for (int j = 0; j < 8; ++j)
                bfr[j] = f2bf(Wt[cur][(g * 8 + j) * 128 + csw]);
#pragma unroll
            for (int mt = 0; mt < 4; ++mt)
                acc[mt][t] = __builtin_amdgcn_mfma_f32_16x16x32_bf16(afr[mt], bfr, acc[mt][t], 0, 0, 0);
        }
        __builtin_amdgcn_s_barrier();    // reads of cur done before overwrite
    }

    // ---- coalesced epilogue: dump C (+bias) to 32KB LDS, store 512B rows ----
    __syncthreads();
    float* Cl = (float*)&Wt[0][0];       // 64 rows x 128 cols = 32 KB
#pragma unroll
    for (int t = 0; t < 2; ++t) {
        const int colb = w * 32 + t * 16 + lr;
        float bb = bias[n0 + colb];
#pragma unroll
        for (int mt = 0; mt < 4; ++mt)
#pragma unroll
            for (int r = 0; r < 4; ++r)
                Cl[(mt * 16 + g * 4 + r) * 128 + colb] = acc[mt][t][r] + bb;
    }
    __syncthreads();
#pragma unroll
    for (int it = 0; it < 8; ++it) {     // 256 thr: 32-lane group per row
        int row = (tid >> 5) + it * 8;   // 0..63
        int cc = (tid & 31) * 4;         // float offset 0..124
        f32x4 v = *(const f32x4*)&Cl[row * 128 + cc];
        *(f32x4*)(f + (size_t)row * NPIX + n0 + cc) = v;
    }
}

// --------------------------- Stencil (two-phase, R17/R19 exact) --------------
#define ROWS 16
__device__ __forceinline__ int rfl(int i) {
    return i < 0 ? -i : (i > 255 ? 510 - i : i);
}
__global__ void k_stencil(const float* __restrict__ f, const float* __restrict__ P,
                          float* __restrict__ out) {
    __shared__ float fs[ROWS + 4][256];
    __shared__ float ls[ROWS + 2][256];
    int x = threadIdx.x;
    int y0 = blockIdx.x * ROWS;
    int b = blockIdx.y;
    const float* fb = f + (size_t)b * NPIX;
#pragma unroll
    for (int t = 0; t < ROWS + 4; ++t) {
        int gy = rfl(y0 - 2 + t);
        fs[t][x] = fb[gy * 256 + x];
    }
    __syncthreads();

    int xm = x == 0 ? 1 : x - 1;
    int xp = x == 255 ? 254 : x + 1;

#pragma unroll
    for (int t = 0; t < ROWS + 2; ++t) {
        int jj = rfl(y0 - 1 + t);
        int s  = jj - y0 + 2;
        int sm = rfl(jj - 1) - y0 + 2;
        int sp = rfl(jj + 1) - y0 + 2;
        float c = fs[s][x];
        ls[t][x] = (fs[sm][x] - 2.f * c + fs[sp][x]) +
                   (fs[s][xm] - 2.f * c + fs[s][xp]);
    }
    __syncthreads();

#pragma unroll
    for (int r = 0; r < ROWS; ++r) {
        int y = y0 + r;
        float lc = ls[r + 1][x];
        float bih = (ls[r][x] - 2.f * lc + ls[r + 2][x]) +
                    (ls[r + 1][xm] - 2.f * lc + ls[r + 1][xp]);
        float fc = fs[r + 2][x];
        size_t idx = (size_t)b * NPIX + y * 256 + x;
        out[idx] = bih + lc + fc - P[idx];
    }
}

extern "C" void kernel_launch(void* const* d_in, const int* in_sizes, int n_in,
                              void* d_out, int out_size, void* d_ws, size_t ws_size,
                              hipStream_t stream) {
    const float* x  = (const float*)d_in[0];
    const float* P  = (const float*)d_in[1];
    const float* W1 = (const float*)d_in[2];
    const float* b1 = (const float*)d_in[3];
    const float* W2 = (const float*)d_in[4];
    const float* b2 = (const float*)d_in[5];
    const float* W3 = (const float*)d_in[6];
    const float* b3 = (const float*)d_in[7];
    const float* W4 = (const float*)d_in[8];
    const float* b4 = (const float*)d_in[9];
    float* out = (float*)d_out;

    char* ws = (char*)d_ws;
    short* h2b = (short*)(ws);                      // 64*512*2  = 64 KB
    short* h3b = (short*)(ws + (128 << 10));        // 64*1024*2 = 128 KB (bf16)
    float* f   = (float*)(ws + (256 << 10));        // 64*65536*4 = 16 MB

    k_layer12<<<512 / 16, 64, 0, stream>>>(x, W1, b1, W2, b2, h2b);
    k_layer3<<<64, 64, 0, stream>>>(h2b, W3, b3, h3b);
    k_gemm_mfma<<<NPIX / 128, 256, 0, stream>>>(h3b, W4, b4, f);
    k_stencil<<<dim3(256 / ROWS, BATCH), 256, 0, stream>>>(f, P, out);
}